// Round 10
// baseline (14051.883 us; speedup 1.0000x reference)
//
#include <hip/hip_runtime.h>
#include <hip/hip_cooperative_groups.h>

namespace cg = cooperative_groups;

#define BB 256
#define SS 512
#define EE 512
#define HH 512
#define G4 2048
#define NTF 799

typedef __attribute__((ext_vector_type(8))) short bf16x8;
typedef __attribute__((ext_vector_type(4))) float f32x4;

__device__ __forceinline__ float my_sig(float v) { return 1.0f / (1.0f + __expf(-v)); }
__device__ __forceinline__ float my_tanh(float v) { float e = __expf(2.0f * v); return 1.0f - 2.0f / (e + 1.0f); }

__device__ __forceinline__ unsigned short f2bf(float f) {   // RNE fp32->bf16
    unsigned u = __builtin_bit_cast(unsigned, f);
    u = (u + 0x7FFFu + ((u >> 16) & 1u)) >> 16;
    return (unsigned short)u;
}
__device__ __forceinline__ float bf2f(unsigned short h) {
    unsigned u = ((unsigned)h) << 16;
    return __builtin_bit_cast(float, u);
}
__device__ __forceinline__ unsigned packsplit(float f) {
    unsigned short hi = f2bf(f);
    unsigned short lo = f2bf(f - bf2f(hi));
    return ((unsigned)hi << 16) | (unsigned)lo;
}
__device__ __forceinline__ bf16x8 unhi(uint4 a, uint4 b) {
    union { unsigned u[4]; bf16x8 v; } r;
    r.u[0] = __builtin_amdgcn_perm(a.y, a.x, 0x07060302u);
    r.u[1] = __builtin_amdgcn_perm(a.w, a.z, 0x07060302u);
    r.u[2] = __builtin_amdgcn_perm(b.y, b.x, 0x07060302u);
    r.u[3] = __builtin_amdgcn_perm(b.w, b.z, 0x07060302u);
    return r.v;
}
__device__ __forceinline__ bf16x8 unlo(uint4 a, uint4 b) {
    union { unsigned u[4]; bf16x8 v; } r;
    r.u[0] = __builtin_amdgcn_perm(a.y, a.x, 0x05040100u);
    r.u[1] = __builtin_amdgcn_perm(a.w, a.z, 0x05040100u);
    r.u[2] = __builtin_amdgcn_perm(b.y, b.x, 0x05040100u);
    r.u[3] = __builtin_amdgcn_perm(b.w, b.z, 0x05040100u);
    return r.v;
}

// sc1 coherent accesses (verified r4-r9)
__device__ __forceinline__ void ld4_sc1(uint4& d, const unsigned* p) {
    asm volatile("global_load_dwordx4 %0, %1, off sc0 sc1" : "=v"(d) : "v"(p));
}
__device__ __forceinline__ void st_devu(unsigned* p, unsigned v) {
    __hip_atomic_store(p, v, __ATOMIC_RELAXED, __HIP_MEMORY_SCOPE_AGENT);
}
__device__ __forceinline__ unsigned ld_devu(const unsigned* p) {
    return __hip_atomic_load(p, __ATOMIC_RELAXED, __HIP_MEMORY_SCOPE_AGENT);
}

// ---------------------------------------------------------------------------
// Prep (verbatim from r8/r9, verified)
// ---------------------------------------------------------------------------
__global__ void __launch_bounds__(256)
prep_split(const float* __restrict__ Wall, const float* __restrict__ Uall,
           const float* __restrict__ Wd,
           unsigned short* __restrict__ B1, unsigned short* __restrict__ B2)
{
    const int t = blockIdx.x * 256 + threadIdx.x;
    if (t < 262144) {
        const int lane = t & 63, wc = (t >> 6) & 3, kc = (t >> 8) & 31, cgi = t >> 13;
        const int kb = ((kc & 15) << 5) + ((lane >> 4) << 3);
        const int col = (wc << 9) + (cgi << 4) + (lane & 15);
        const float* src = (kc < 16) ? Wall : Uall;
        bf16x8 vh, vl;
#pragma unroll
        for (int j = 0; j < 8; ++j) {
            float f = src[(size_t)(kb + j) * G4 + col];
            unsigned short h16 = f2bf(f);
            vh[j] = (short)h16;
            vl[j] = (short)f2bf(f - bf2f(h16));
        }
        const int g = t >> 6;
        *(bf16x8*)(B1 + ((size_t)(g * 2 + 0) * 64 + lane) * 8) = vh;
        *(bf16x8*)(B1 + ((size_t)(g * 2 + 1) * 64 + lane) * 8) = vl;
    } else if (t < 262144 + 32768) {
        const int u = t - 262144;
        const int lane = u & 63, kch = (u >> 6) & 15, cgi = u >> 10;
        const int kb = (kch << 5) + ((lane >> 4) << 3);
        const int col = (cgi << 4) + (lane & 15);
        bf16x8 vh, vl;
#pragma unroll
        for (int j = 0; j < 8; ++j) {
            float f = Wd[(size_t)(kb + j) * HH + col];
            unsigned short h16 = f2bf(f);
            vh[j] = (short)h16;
            vl[j] = (short)f2bf(f - bf2f(h16));
        }
        const int g = u >> 6;
        *(bf16x8*)(B2 + ((size_t)(g * 2 + 0) * 64 + lane) * 8) = vh;
        *(bf16x8*)(B2 + ((size_t)(g * 2 + 1) * 64 + lane) * 8) = vl;
    }
}

#define B1FRAG(kcv, wcv, term) (*(const bf16x8*)(B1 +                          \
    ((size_t)(((cgi * 32 + (kcv)) * 4 + (wcv)) * 2 + (term)) * 64 + lane) * 8))
#define B2FRAG(kchv, term) (*(const bf16x8*)(B2 +                              \
    ((size_t)((cgi * 16 + (kchv)) * 2 + (term)) * 64 + lane) * 8))

// gate-partial LDS index with bank-spreading XOR hash (2-way max = free)
#define GPIDX(row, slot, col)                                                  \
    ((row) * 512 + (slot) * 64 + ((col) ^ (((((row) & 3) ^ (((row) >> 2) & 3))) << 4)))

// GEMM1 partial MFMAs over one staged region; wave K-window = wq*128..+128
#define DO_G1(ACC, Rv)                                                         \
    _Pragma("unroll")                                                          \
    for (int q = 0; q < 4; ++q) {                                              \
        _Pragma("unroll")                                                      \
        for (int wr = 0; wr < 2; ++wr) {                                       \
            const int row_ = (wr << 4) | lrow;                                 \
            const int cb_  = (((wq << 2) + q) << 3) + (lk8 << 1);              \
            uint4 qa = Rv[row_ * 128 + (cb_ ^ (row_ & 7))];                    \
            uint4 qb = Rv[row_ * 128 + ((cb_ + 1) ^ (row_ & 7))];              \
            bf16x8 ah = unhi(qa, qb), al = unlo(qa, qb);                       \
            _Pragma("unroll")                                                  \
            for (int wc = 0; wc < 4; ++wc) {                                   \
                ACC[wr][wc] = __builtin_amdgcn_mfma_f32_16x16x32_bf16(ah, b1h[q][wc], ACC[wr][wc], 0, 0, 0); \
                ACC[wr][wc] = __builtin_amdgcn_mfma_f32_16x16x32_bf16(ah, b1l[q][wc], ACC[wr][wc], 0, 0, 0); \
                ACC[wr][wc] = __builtin_amdgcn_mfma_f32_16x16x32_bf16(al, b1h[q][wc], ACC[wr][wc], 0, 0, 0); \
            }                                                                  \
        }                                                                      \
    }

// ---------------------------------------------------------------------------
// Persistent time-LSTM. 256 blocks x 512 threads. Roles: waves 0-3 = x-side
// (U-frags, accX, B2-frags, G2); waves 4-7 = h-side (W-frags, accH).
// Per step: [stage AX | x-MFMA] -> wait release -> [load h+c, stage AH,AC] ->
// [h-MFMA || G2-MFMA] -> [partial writes] -> [reduce + update + stores] ->
// [drain + hierarchical arrival].
// ---------------------------------------------------------------------------
__global__ void __launch_bounds__(512, 2)
lstm_persistent(const float* __restrict__ x, const float* __restrict__ ts,
                const float* __restrict__ ball, const float* __restrict__ bu,
                const float* __restrict__ bd,
                const unsigned short* __restrict__ B1,
                const unsigned short* __restrict__ B2,
                unsigned* __restrict__ h2a, unsigned* __restrict__ h2b,
                unsigned* __restrict__ c2a, unsigned* __restrict__ c2b,
                float* __restrict__ hsum, float* __restrict__ tsT,
                unsigned* __restrict__ barv)
{
    cg::grid_group grid = cg::this_grid();
    const int tid = threadIdx.x;
    const int bid = blockIdx.x;
    const int gtid = (bid << 9) + tid;

    for (int i = gtid; i < BB * HH; i += 131072) { h2a[i] = 0u; c2a[i] = 0u; }
    for (int i = gtid; i < BB * SS; i += 131072) {
        int b = i >> 9, s = i & 511;
        tsT[s * BB + b] = ts[i];
    }
    if (gtid < 1024) barv[gtid] = 0u;
    grid.sync();

    // XCD-aware bijective relabeling (perf heuristic only)
    const int xcd = bid & 7, tt = bid >> 3;
    const int cgi = (xcd << 2) | (tt & 3);   // 0..31 -> m0
    const int rg  = tt >> 2;                 // 0..7  -> r0
    const int r0  = rg << 5;
    const int m0  = cgi << 4;

    const int wid = tid >> 6, lane = tid & 63;
    const int lrow = lane & 15, lk8 = lane >> 4;
    const int wq  = (wid < 4) ? wid : (wid - 4);
    const int srow = tid >> 4, scb = tid & 15;
    const int rl = srow, mj = scb;

    __shared__ __align__(16) unsigned R1[32 * 512];  // AX -> AC -> gp2(cs1 partials)
    __shared__ __align__(16) unsigned R2[32 * 512];  // AH -> gp (gate partials)
    uint4* R1v = (uint4*)R1;
    uint4* R2v = (uint4*)R2;
    float* gp  = (float*)R2;
    float* gp2 = (float*)R1;

    // hierarchical barrier storage (cacheline-spread)
    unsigned* arr = barv;              // arr[g]  at barv[g*32]
    unsigned* gar = barv + 256;        // global arrival counter
    unsigned* rel = barv + 288;        // rel[g]  at barv[288 + g*32]
    const int grp = bid & 7;

    // register-resident weights: waves 0-3 hold Uall (kc 16..31) + Wd; 4-7 Wall
    bf16x8 b1h[4][4], b1l[4][4], b2h[4], b2l[4];
    const int kcb = (wid < 4) ? (16 + (wid << 2)) : ((wid - 4) << 2);
#pragma unroll
    for (int q = 0; q < 4; ++q)
#pragma unroll
        for (int wc = 0; wc < 4; ++wc) {
            b1h[q][wc] = B1FRAG(kcb + q, wc, 0);
            b1l[q][wc] = B1FRAG(kcb + q, wc, 1);
        }
    if (wid < 4) {
#pragma unroll
        for (int q = 0; q < 4; ++q) {
            b2h[q] = B2FRAG((wid << 2) + q, 0);
            b2l[q] = B2FRAG((wid << 2) + q, 1);
        }
    }

    float bias4[4];
#pragma unroll
    for (int k = 0; k < 4; ++k)
        bias4[k] = ball[(k << 9) + m0 + mj] + bu[(k << 9) + m0 + mj];
    const float bias2v = bd[m0 + mj];

    float creg = 0.f, hsreg = 0.f;

#pragma unroll 1
    for (int s = 0; s < SS; ++s) {
        const unsigned* h2p = (s & 1) ? h2b : h2a;
        const unsigned* c2p = (s & 1) ? c2b : c2a;
        unsigned* h2n = (s & 1) ? h2a : h2b;
        unsigned* c2n = (s & 1) ? c2a : c2b;

        // ---- A: stage AX <- x(s) ----
        __syncthreads();                      // R1/R2 reads of prev step done
        {
            const float* xp = x + (size_t)(r0 + srow) * (SS * EE) + (size_t)s * EE;
#pragma unroll
            for (int j = 0; j < 8; ++j) {
                const int ci = scb + (j << 4);
                float4 v = *(const float4*)(xp + (ci << 2));
                uint4 pk;
                pk.x = packsplit(v.x); pk.y = packsplit(v.y);
                pk.z = packsplit(v.z); pk.w = packsplit(v.w);
                R1v[srow * 128 + (ci ^ (srow & 7))] = pk;
            }
        }
        __syncthreads();

        // ---- x-partial MFMAs (waves 0-3) ----
        f32x4 accX[2][4];
        if (wid < 4) {
#pragma unroll
            for (int wr = 0; wr < 2; ++wr)
#pragma unroll
                for (int wc = 0; wc < 4; ++wc) accX[wr][wc] = (f32x4){0.f, 0.f, 0.f, 0.f};
            DO_G1(accX, R1v);
        }

        // ---- B: wait release for step s (group-local flag, 32 pollers/line) ----
        if (tid == 0) {
            while (ld_devu(&rel[grp * 32]) < (unsigned)s)
                __builtin_amdgcn_s_sleep(4);
        }
        __syncthreads();
        asm volatile("" ::: "memory");

        // ---- C: load h(s) and c(s) (packed), stage AH -> R2, AC -> R1 ----
        {
            const unsigned* hp = h2p + (r0 + srow) * HH;
            uint4 hv[8];
#pragma unroll
            for (int j = 0; j < 8; ++j) ld4_sc1(hv[j], hp + ((scb + (j << 4)) << 2));
            asm volatile("s_waitcnt vmcnt(0)" ::: "memory");
            __builtin_amdgcn_sched_barrier(0);
#pragma unroll
            for (int j = 0; j < 8; ++j) {
                const int ci = scb + (j << 4);
                R2v[srow * 128 + (ci ^ (srow & 7))] = hv[j];
            }
        }
        {
            const unsigned* cp = c2p + (r0 + srow) * HH;
            uint4 cv[8];
#pragma unroll
            for (int j = 0; j < 8; ++j) ld4_sc1(cv[j], cp + ((scb + (j << 4)) << 2));
            asm volatile("s_waitcnt vmcnt(0)" ::: "memory");
            __builtin_amdgcn_sched_barrier(0);
#pragma unroll
            for (int j = 0; j < 8; ++j) {
                const int ci = scb + (j << 4);
                R1v[srow * 128 + (ci ^ (srow & 7))] = cv[j];
            }
        }
        __syncthreads();

        // ---- D: h-MFMA (waves 4-7, R2) || G2 c.Wd MFMA (waves 0-3, R1) ----
        f32x4 accH[2][4];
        f32x4 acc2[2];
        if (wid >= 4) {
#pragma unroll
            for (int wr = 0; wr < 2; ++wr)
#pragma unroll
                for (int wc = 0; wc < 4; ++wc) accH[wr][wc] = (f32x4){0.f, 0.f, 0.f, 0.f};
            DO_G1(accH, R2v);
        } else {
            acc2[0] = (f32x4){0.f, 0.f, 0.f, 0.f};
            acc2[1] = (f32x4){0.f, 0.f, 0.f, 0.f};
#pragma unroll
            for (int q = 0; q < 4; ++q)
#pragma unroll
                for (int wr = 0; wr < 2; ++wr) {
                    const int row_ = (wr << 4) | lrow;
                    const int cb_  = (((wid << 2) + q) << 3) + (lk8 << 1);
                    uint4 qa = R1v[row_ * 128 + (cb_ ^ (row_ & 7))];
                    uint4 qb = R1v[row_ * 128 + ((cb_ + 1) ^ (row_ & 7))];
                    bf16x8 ah = unhi(qa, qb), al = unlo(qa, qb);
                    acc2[wr] = __builtin_amdgcn_mfma_f32_16x16x32_bf16(ah, b2h[q], acc2[wr], 0, 0, 0);
                    acc2[wr] = __builtin_amdgcn_mfma_f32_16x16x32_bf16(ah, b2l[q], acc2[wr], 0, 0, 0);
                    acc2[wr] = __builtin_amdgcn_mfma_f32_16x16x32_bf16(al, b2h[q], acc2[wr], 0, 0, 0);
                }
        }
        __syncthreads();

        // ---- E: partial writes. gp -> R2 (slots 0-3 = h, 4-7 = x); gp2 -> R1 ----
        if (wid >= 4) {
#pragma unroll
            for (int wr = 0; wr < 2; ++wr)
#pragma unroll
                for (int wc = 0; wc < 4; ++wc)
#pragma unroll
                    for (int i = 0; i < 4; ++i)
                        gp[GPIDX((wr << 4) + (lk8 << 2) + i, wid - 4, (wc << 4) + lrow)] = accH[wr][wc][i];
        } else {
#pragma unroll
            for (int wr = 0; wr < 2; ++wr)
#pragma unroll
                for (int wc = 0; wc < 4; ++wc)
#pragma unroll
                    for (int i = 0; i < 4; ++i)
                        gp[GPIDX((wr << 4) + (lk8 << 2) + i, 4 + wid, (wc << 4) + lrow)] = accX[wr][wc][i];
#pragma unroll
            for (int wr = 0; wr < 2; ++wr)
#pragma unroll
                for (int i = 0; i < 4; ++i)
                    gp2[((wr << 4) + (lk8 << 2) + i) * 64 + (wid << 4) + lrow] = acc2[wr][i];
        }
        __syncthreads();

        // ---- F: reduce + update + sc1 stores ----
        {
            float gv[4];
#pragma unroll
            for (int k = 0; k < 4; ++k) {
                float sacc = bias4[k];
#pragma unroll
                for (int p = 0; p < 8; ++p)
                    sacc += gp[GPIDX(rl, p, (k << 4) + mj)];
                gv[k] = my_sig(sacc);
            }
            float sacc2 = bias2v;
#pragma unroll
            for (int p = 0; p < 4; ++p)
                sacc2 += gp2[rl * 64 + (p << 4) + mj];
            const float cs1v = my_tanh(sacc2);
            const float tv = tsT[s * BB + r0 + rl];
            const float cadj = creg + cs1v * (tv - 1.0f);
            const float cnew = gv[0] * cadj + gv[1] * gv[3];
            const float hnew = gv[2] * my_tanh(cnew);
            creg = cnew; hsreg += hnew;
            const int gidx = (r0 + rl) * HH + m0 + mj;
            st_devu(&c2n[gidx], packsplit(cnew));
            st_devu(&h2n[gidx], packsplit(hnew));
        }

        // ---- G: drain stores + hierarchical arrival ----
        asm volatile("s_waitcnt vmcnt(0)" ::: "memory");
        __syncthreads();
        if (tid == 0) {
            unsigned old = __hip_atomic_fetch_add(&arr[grp * 32], 1u,
                                                  __ATOMIC_RELAXED, __HIP_MEMORY_SCOPE_AGENT);
            if (old == 32u * (unsigned)(s + 1) - 1u) {
                unsigned go = __hip_atomic_fetch_add(gar, 1u,
                                                     __ATOMIC_RELAXED, __HIP_MEMORY_SCOPE_AGENT);
                if (go == 8u * (unsigned)(s + 1) - 1u) {
#pragma unroll
                    for (int g = 0; g < 8; ++g)
                        st_devu(&rel[g * 32], (unsigned)(s + 1));
                }
            }
        }
    }

    hsum[(r0 + rl) * HH + m0 + mj] = hsreg;
}

// Tail: sub = relu(tfidf@fcw+b); x = [sub | hsum/512]; 3-layer MLP (fp32).
__global__ void __launch_bounds__(256)
tail_kernel(const float* __restrict__ tfidf, const float* __restrict__ hsum,
            const float* __restrict__ fcw, const float* __restrict__ fcb,
            const float* __restrict__ l1w, const float* __restrict__ l1b,
            const float* __restrict__ l2w, const float* __restrict__ l2b,
            const float* __restrict__ low, const float* __restrict__ lob,
            float* __restrict__ out)
{
    const int row = blockIdx.x;
    const int t = threadIdx.x;
    __shared__ float tf[800];
    __shared__ float xrow[1024];
    __shared__ float y1[256];
    __shared__ float y2[128];

    for (int k = t; k < NTF; k += 256) tf[k] = tfidf[row * NTF + k];
    __syncthreads();

    for (int n = t; n < 512; n += 256) {
        float acc = fcb[n];
        for (int k = 0; k < NTF; ++k) acc += tf[k] * fcw[k * 512 + n];
        xrow[n] = fmaxf(acc, 0.f);
    }
    for (int n = t; n < 512; n += 256)
        xrow[512 + n] = hsum[row * HH + n] * (1.0f / 512.0f);
    __syncthreads();

    {
        float acc = l1b[t];
        for (int k = 0; k < 1024; ++k) acc += xrow[k] * l1w[k * 256 + t];
        y1[t] = fmaxf(acc, 0.f);
    }
    __syncthreads();
    if (t < 128) {
        float acc = l2b[t];
        for (int k = 0; k < 256; ++k) acc += y1[k] * l2w[k * 128 + t];
        y2[t] = fmaxf(acc, 0.f);
    }
    __syncthreads();
    if (t < 2) {
        float acc = lob[t];
        for (int k = 0; k < 128; ++k) acc += y2[k] * low[k * 2 + t];
        out[row * 2 + t] = acc;
    }
}

extern "C" void kernel_launch(void* const* d_in, const int* in_sizes, int n_in,
                              void* d_out, int out_size, void* d_ws, size_t ws_size,
                              hipStream_t stream)
{
    const float* x     = (const float*)d_in[0];
    const float* ts    = (const float*)d_in[1];
    const float* tfidf = (const float*)d_in[2];
    const float* Wall  = (const float*)d_in[3];
    const float* ball  = (const float*)d_in[4];
    const float* Uall  = (const float*)d_in[5];
    const float* bu    = (const float*)d_in[6];
    const float* Wd    = (const float*)d_in[7];
    const float* bd    = (const float*)d_in[8];
    const float* fcw   = (const float*)d_in[9];
    const float* fcb   = (const float*)d_in[10];
    const float* l1w   = (const float*)d_in[11];
    const float* l1b   = (const float*)d_in[12];
    const float* l2w   = (const float*)d_in[13];
    const float* l2b   = (const float*)d_in[14];
    const float* low   = (const float*)d_in[15];
    const float* lob   = (const float*)d_in[16];
    float* out = (float*)d_out;

    unsigned* wsu = (unsigned*)d_ws;
    unsigned* h2a = wsu;
    unsigned* h2b = h2a + BB * HH;
    unsigned* c2a = h2b + BB * HH;
    unsigned* c2b = c2a + BB * HH;
    float* hs  = (float*)(c2b + BB * HH);
    float* tsT = hs + BB * HH;
    unsigned* barv = (unsigned*)(tsT + BB * SS);               // 1024 u32
    unsigned short* B1 = (unsigned short*)(barv + 1024);
    unsigned short* B2 = B1 + (size_t)32 * 32 * 4 * 2 * 64 * 8;  // B1 = 16.8MB

    prep_split<<<1152, 256, 0, stream>>>(Wall, Uall, Wd, B1, B2);

    void* args[] = { (void*)&x, (void*)&ts, (void*)&ball, (void*)&bu, (void*)&bd,
                     (void*)&B1, (void*)&B2,
                     (void*)&h2a, (void*)&h2b, (void*)&c2a, (void*)&c2b,
                     (void*)&hs, (void*)&tsT, (void*)&barv };
    hipLaunchCooperativeKernel((void*)lstm_persistent, dim3(256), dim3(512), args, 0, stream);

    tail_kernel<<<256, 256, 0, stream>>>(tfidf, hs, fcw, fcb, l1w, l1b, l2w, l2b,
                                         low, lob, out);
}

// Round 11
// 6437.846 us; speedup vs baseline: 2.1827x; 2.1827x over previous
//
#include <hip/hip_runtime.h>
#include <hip/hip_cooperative_groups.h>

namespace cg = cooperative_groups;

#define BB 256
#define SS 512
#define EE 512
#define HH 512
#define G4 2048
#define NTF 799

typedef __attribute__((ext_vector_type(8))) short bf16x8;
typedef __attribute__((ext_vector_type(4))) float f32x4;

__device__ __forceinline__ float my_sig(float v) { return 1.0f / (1.0f + __expf(-v)); }
__device__ __forceinline__ float my_tanh(float v) { float e = __expf(2.0f * v); return 1.0f - 2.0f / (e + 1.0f); }

__device__ __forceinline__ unsigned short f2bf(float f) {   // RNE fp32->bf16
    unsigned u = __builtin_bit_cast(unsigned, f);
    u = (u + 0x7FFFu + ((u >> 16) & 1u)) >> 16;
    return (unsigned short)u;
}
__device__ __forceinline__ float bf2f(unsigned short h) {
    unsigned u = ((unsigned)h) << 16;
    return __builtin_bit_cast(float, u);
}
__device__ __forceinline__ unsigned packsplit(float f) {
    unsigned short hi = f2bf(f);
    unsigned short lo = f2bf(f - bf2f(hi));
    return ((unsigned)hi << 16) | (unsigned)lo;
}
__device__ __forceinline__ bf16x8 unhi(uint4 a, uint4 b) {
    union { unsigned u[4]; bf16x8 v; } r;
    r.u[0] = __builtin_amdgcn_perm(a.y, a.x, 0x07060302u);
    r.u[1] = __builtin_amdgcn_perm(a.w, a.z, 0x07060302u);
    r.u[2] = __builtin_amdgcn_perm(b.y, b.x, 0x07060302u);
    r.u[3] = __builtin_amdgcn_perm(b.w, b.z, 0x07060302u);
    return r.v;
}
__device__ __forceinline__ bf16x8 unlo(uint4 a, uint4 b) {
    union { unsigned u[4]; bf16x8 v; } r;
    r.u[0] = __builtin_amdgcn_perm(a.y, a.x, 0x05040100u);
    r.u[1] = __builtin_amdgcn_perm(a.w, a.z, 0x05040100u);
    r.u[2] = __builtin_amdgcn_perm(b.y, b.x, 0x05040100u);
    r.u[3] = __builtin_amdgcn_perm(b.w, b.z, 0x05040100u);
    return r.v;
}

// sc1 coherent accesses (verified r4-r10)
__device__ __forceinline__ void ld4_sc1(uint4& d, const unsigned* p) {
    asm volatile("global_load_dwordx4 %0, %1, off sc0 sc1" : "=v"(d) : "v"(p));
}
__device__ __forceinline__ void st_devu(unsigned* p, unsigned v) {
    __hip_atomic_store(p, v, __ATOMIC_RELAXED, __HIP_MEMORY_SCOPE_AGENT);
}
__device__ __forceinline__ unsigned ld_devu(const unsigned* p) {
    return __hip_atomic_load(p, __ATOMIC_RELAXED, __HIP_MEMORY_SCOPE_AGENT);
}

// ---------------------------------------------------------------------------
// Prep (verbatim r8-r10, verified)
// ---------------------------------------------------------------------------
__global__ void __launch_bounds__(256)
prep_split(const float* __restrict__ Wall, const float* __restrict__ Uall,
           const float* __restrict__ Wd,
           unsigned short* __restrict__ B1, unsigned short* __restrict__ B2)
{
    const int t = blockIdx.x * 256 + threadIdx.x;
    if (t < 262144) {
        const int lane = t & 63, wc = (t >> 6) & 3, kc = (t >> 8) & 31, cgi = t >> 13;
        const int kb = ((kc & 15) << 5) + ((lane >> 4) << 3);
        const int col = (wc << 9) + (cgi << 4) + (lane & 15);
        const float* src = (kc < 16) ? Wall : Uall;
        bf16x8 vh, vl;
#pragma unroll
        for (int j = 0; j < 8; ++j) {
            float f = src[(size_t)(kb + j) * G4 + col];
            unsigned short h16 = f2bf(f);
            vh[j] = (short)h16;
            vl[j] = (short)f2bf(f - bf2f(h16));
        }
        const int g = t >> 6;
        *(bf16x8*)(B1 + ((size_t)(g * 2 + 0) * 64 + lane) * 8) = vh;
        *(bf16x8*)(B1 + ((size_t)(g * 2 + 1) * 64 + lane) * 8) = vl;
    } else if (t < 262144 + 32768) {
        const int u = t - 262144;
        const int lane = u & 63, kch = (u >> 6) & 15, cgi = u >> 10;
        const int kb = (kch << 5) + ((lane >> 4) << 3);
        const int col = (cgi << 4) + (lane & 15);
        bf16x8 vh, vl;
#pragma unroll
        for (int j = 0; j < 8; ++j) {
            float f = Wd[(size_t)(kb + j) * HH + col];
            unsigned short h16 = f2bf(f);
            vh[j] = (short)h16;
            vl[j] = (short)f2bf(f - bf2f(h16));
        }
        const int g = u >> 6;
        *(bf16x8*)(B2 + ((size_t)(g * 2 + 0) * 64 + lane) * 8) = vh;
        *(bf16x8*)(B2 + ((size_t)(g * 2 + 1) * 64 + lane) * 8) = vl;
    }
}

#define B1FRAG(kcv, wcv, term) (*(const bf16x8*)(B1 +                          \
    ((size_t)(((cgi * 32 + (kcv)) * 4 + (wcv)) * 2 + (term)) * 64 + lane) * 8))
#define B2FRAG(kchv, term) (*(const bf16x8*)(B2 +                              \
    ((size_t)((cgi * 16 + (kchv)) * 2 + (term)) * 64 + lane) * 8))

// gate-partial LDS index, bank-hashed (2-way max = free)
#define GPIDX(row, slot, col)                                                  \
    ((row) * 256 + (slot) * 64 + ((col) ^ (((((row) & 3) ^ (((row) >> 2) & 3))) << 4)))

// ---------------------------------------------------------------------------
// Persistent time-LSTM. 256 blocks x 512 threads. Wave (kq=wid&3, ch=wid>>2):
// K-window kq*128..+128, gate-cols ch*32..+32. Register-resident: W frags
// (64 VGPR) + Wd frags (16 VGPR). U frags streamed from (XCD-local) L2 per
// step, double-buffered, hidden under phase-A MFMAs. x.U and h.W accumulate
// into ONE acc -> one partial write, 4-slot reduce. ~190 VGPR peak (no spill).
// ---------------------------------------------------------------------------
__global__ void __launch_bounds__(512) __attribute__((amdgpu_waves_per_eu(2)))
lstm_persistent(const float* __restrict__ x, const float* __restrict__ ts,
                const float* __restrict__ ball, const float* __restrict__ bu,
                const float* __restrict__ bd,
                const unsigned short* __restrict__ B1,
                const unsigned short* __restrict__ B2,
                unsigned* __restrict__ h2a, unsigned* __restrict__ h2b,
                unsigned* __restrict__ c2a, unsigned* __restrict__ c2b,
                float* __restrict__ hsum, float* __restrict__ tsT,
                unsigned* __restrict__ barv)
{
    cg::grid_group grid = cg::this_grid();
    const int tid = threadIdx.x;
    const int bid = blockIdx.x;
    const int gtid = (bid << 9) + tid;

    for (int i = gtid; i < BB * HH; i += 131072) { h2a[i] = 0u; c2a[i] = 0u; }
    for (int i = gtid; i < BB * SS; i += 131072) {
        int b = i >> 9, s = i & 511;
        tsT[s * BB + b] = ts[i];
    }
    if (gtid < 1024) barv[gtid] = 0u;
    grid.sync();

    // XCD-aware bijective relabeling: blocks sharing cgi sit on ONE XCD ->
    // that XCD's L2 keeps the 4 x 256KB B1 slices resident (U streaming hits L2)
    const int xcd = bid & 7, tt = bid >> 3;
    const int cgi = (xcd << 2) | (tt & 3);   // 0..31 -> m0
    const int rg  = tt >> 2;                 // 0..7  -> r0
    const int r0  = rg << 5;
    const int m0  = cgi << 4;

    const int wid = tid >> 6, lane = tid & 63;
    const int lrow = lane & 15, lk8 = lane >> 4;
    const int kq = wid & 3, ch = wid >> 2;   // K-window / col-half
    const int srow = tid >> 4, scb = tid & 15;
    const int rl = srow, mj = scb;

    __shared__ __align__(16) unsigned R1[32 * 512];  // AX -> AC
    __shared__ __align__(16) unsigned R2[32 * 512];  // AH -> partials
    uint4* R1v = (uint4*)R1;
    uint4* R2v = (uint4*)R2;
    float* gp  = (float*)R2;              // [32][4][64] hashed, 32KB
    float* gp2 = (float*)(R2 + 8192);     // [32][132], 17KB

    // hierarchical barrier storage (cacheline-spread)
    unsigned* arr = barv;
    unsigned* gar = barv + 256;
    unsigned* rel = barv + 288;
    const int grp = bid & 7;

    // register-resident: W frags (kc 0..15 -> this wave's kq*4..+3) + Wd
    bf16x8 wfh[4][2], wfl[4][2], d2h[2], d2l[2];
#pragma unroll
    for (int q = 0; q < 4; ++q)
#pragma unroll
        for (int wcl = 0; wcl < 2; ++wcl) {
            wfh[q][wcl] = B1FRAG((kq << 2) + q, (ch << 1) + wcl, 0);
            wfl[q][wcl] = B1FRAG((kq << 2) + q, (ch << 1) + wcl, 1);
        }
#pragma unroll
    for (int e = 0; e < 2; ++e) {
        d2h[e] = B2FRAG((wid << 1) + e, 0);
        d2l[e] = B2FRAG((wid << 1) + e, 1);
    }

    float bias4[4];
#pragma unroll
    for (int k = 0; k < 4; ++k)
        bias4[k] = ball[(k << 9) + m0 + mj] + bu[(k << 9) + m0 + mj];
    const float bias2v = bd[m0 + mj];

    float creg = 0.f, hsreg = 0.f;

#pragma unroll 1
    for (int s = 0; s < SS; ++s) {
        const unsigned* h2p = (s & 1) ? h2b : h2a;
        const unsigned* c2p = (s & 1) ? c2b : c2a;
        unsigned* h2n = (s & 1) ? h2a : h2b;
        unsigned* c2n = (s & 1) ? c2a : c2b;

        // ---- A: stage AX <- x(s) ----
        __syncthreads();                      // prev-step partial reads done
        {
            const float* xp = x + (size_t)(r0 + srow) * (SS * EE) + (size_t)s * EE;
#pragma unroll
            for (int j = 0; j < 8; ++j) {
                const int ci = scb + (j << 4);
                float4 v = *(const float4*)(xp + (ci << 2));
                uint4 pk;
                pk.x = packsplit(v.x); pk.y = packsplit(v.y);
                pk.z = packsplit(v.z); pk.w = packsplit(v.w);
                R1v[srow * 128 + (ci ^ (srow & 7))] = pk;
            }
        }
        __syncthreads();

        // ---- phase A: x.U MFMAs, U frags streamed (double-buffered) ----
        f32x4 acc[2][2];
        acc[0][0] = acc[0][1] = acc[1][0] = acc[1][1] = (f32x4){0.f, 0.f, 0.f, 0.f};
        {
            bf16x8 ufh[2][2], ufl[2][2];
#pragma unroll
            for (int wcl = 0; wcl < 2; ++wcl) {
                ufh[0][wcl] = B1FRAG(16 + (kq << 2), (ch << 1) + wcl, 0);
                ufl[0][wcl] = B1FRAG(16 + (kq << 2), (ch << 1) + wcl, 1);
            }
#pragma unroll
            for (int q = 0; q < 4; ++q) {
                const int cur = q & 1, nxt = cur ^ 1;
                if (q < 3) {
#pragma unroll
                    for (int wcl = 0; wcl < 2; ++wcl) {
                        ufh[nxt][wcl] = B1FRAG(16 + (kq << 2) + q + 1, (ch << 1) + wcl, 0);
                        ufl[nxt][wcl] = B1FRAG(16 + (kq << 2) + q + 1, (ch << 1) + wcl, 1);
                    }
                }
                const int kcp = (kq << 2) + q;
#pragma unroll
                for (int wr = 0; wr < 2; ++wr) {
                    const int row_ = (wr << 4) | lrow;
                    const int cb_  = (kcp << 3) + (lk8 << 1);
                    uint4 qa = R1v[row_ * 128 + (cb_ ^ (row_ & 7))];
                    uint4 qb = R1v[row_ * 128 + ((cb_ + 1) ^ (row_ & 7))];
                    bf16x8 ah = unhi(qa, qb), al = unlo(qa, qb);
#pragma unroll
                    for (int wcl = 0; wcl < 2; ++wcl) {
                        acc[wr][wcl] = __builtin_amdgcn_mfma_f32_16x16x32_bf16(ah, ufh[cur][wcl], acc[wr][wcl], 0, 0, 0);
                        acc[wr][wcl] = __builtin_amdgcn_mfma_f32_16x16x32_bf16(ah, ufl[cur][wcl], acc[wr][wcl], 0, 0, 0);
                        acc[wr][wcl] = __builtin_amdgcn_mfma_f32_16x16x32_bf16(al, ufh[cur][wcl], acc[wr][wcl], 0, 0, 0);
                    }
                }
            }
        }

        // ---- B: wait release for step s ----
        if (tid == 0) {
            while (ld_devu(&rel[grp * 32]) < (unsigned)s)
                __builtin_amdgcn_s_sleep(4);
        }
        __syncthreads();
        asm volatile("" ::: "memory");

        // ---- C: load h(s), c(s) (packed sc1), stage AH -> R2, AC -> R1 ----
        {
            const unsigned* hp = h2p + (r0 + srow) * HH;
            uint4 hv[8];
#pragma unroll
            for (int j = 0; j < 8; ++j) ld4_sc1(hv[j], hp + ((scb + (j << 4)) << 2));
            asm volatile("s_waitcnt vmcnt(0)" ::: "memory");
            __builtin_amdgcn_sched_barrier(0);
#pragma unroll
            for (int j = 0; j < 8; ++j) {
                const int ci = scb + (j << 4);
                R2v[srow * 128 + (ci ^ (srow & 7))] = hv[j];
            }
        }
        {
            const unsigned* cp = c2p + (r0 + srow) * HH;
            uint4 cv[8];
#pragma unroll
            for (int j = 0; j < 8; ++j) ld4_sc1(cv[j], cp + ((scb + (j << 4)) << 2));
            asm volatile("s_waitcnt vmcnt(0)" ::: "memory");
            __builtin_amdgcn_sched_barrier(0);
#pragma unroll
            for (int j = 0; j < 8; ++j) {
                const int ci = scb + (j << 4);
                R1v[srow * 128 + (ci ^ (srow & 7))] = cv[j];
            }
        }
        __syncthreads();

        // ---- phase B: h.W MFMAs (resident frags) into same acc; then G2 ----
#pragma unroll
        for (int q = 0; q < 4; ++q) {
            const int kcp = (kq << 2) + q;
#pragma unroll
            for (int wr = 0; wr < 2; ++wr) {
                const int row_ = (wr << 4) | lrow;
                const int cb_  = (kcp << 3) + (lk8 << 1);
                uint4 qa = R2v[row_ * 128 + (cb_ ^ (row_ & 7))];
                uint4 qb = R2v[row_ * 128 + ((cb_ + 1) ^ (row_ & 7))];
                bf16x8 ah = unhi(qa, qb), al = unlo(qa, qb);
#pragma unroll
                for (int wcl = 0; wcl < 2; ++wcl) {
                    acc[wr][wcl] = __builtin_amdgcn_mfma_f32_16x16x32_bf16(ah, wfh[q][wcl], acc[wr][wcl], 0, 0, 0);
                    acc[wr][wcl] = __builtin_amdgcn_mfma_f32_16x16x32_bf16(ah, wfl[q][wcl], acc[wr][wcl], 0, 0, 0);
                    acc[wr][wcl] = __builtin_amdgcn_mfma_f32_16x16x32_bf16(al, wfh[q][wcl], acc[wr][wcl], 0, 0, 0);
                }
            }
        }
        f32x4 acc2[2];
        acc2[0] = (f32x4){0.f, 0.f, 0.f, 0.f};
        acc2[1] = (f32x4){0.f, 0.f, 0.f, 0.f};
#pragma unroll
        for (int e = 0; e < 2; ++e) {
            const int kch = (wid << 1) + e;
#pragma unroll
            for (int wr = 0; wr < 2; ++wr) {
                const int row_ = (wr << 4) | lrow;
                const int cb_  = (kch << 3) + (lk8 << 1);
                uint4 qa = R1v[row_ * 128 + (cb_ ^ (row_ & 7))];
                uint4 qb = R1v[row_ * 128 + ((cb_ + 1) ^ (row_ & 7))];
                bf16x8 ah = unhi(qa, qb), al = unlo(qa, qb);
                acc2[wr] = __builtin_amdgcn_mfma_f32_16x16x32_bf16(ah, d2h[e], acc2[wr], 0, 0, 0);
                acc2[wr] = __builtin_amdgcn_mfma_f32_16x16x32_bf16(ah, d2l[e], acc2[wr], 0, 0, 0);
                acc2[wr] = __builtin_amdgcn_mfma_f32_16x16x32_bf16(al, d2h[e], acc2[wr], 0, 0, 0);
            }
        }
        __syncthreads();   // all AH/AC reads done before partials overwrite R2

        // ---- E: partial writes (gp: slot=kq; gp2: slot=wid) ----
#pragma unroll
        for (int wr = 0; wr < 2; ++wr)
#pragma unroll
            for (int wcl = 0; wcl < 2; ++wcl)
#pragma unroll
                for (int i = 0; i < 4; ++i)
                    gp[GPIDX((wr << 4) + (lk8 << 2) + i, kq, ((ch << 1) + wcl) * 16 + lrow)] = acc[wr][wcl][i];
#pragma unroll
        for (int wr = 0; wr < 2; ++wr)
#pragma unroll
            for (int i = 0; i < 4; ++i)
                gp2[((wr << 4) + (lk8 << 2) + i) * 132 + (wid << 4) + lrow] = acc2[wr][i];
        __syncthreads();

        // ---- F: reduce + update + sc1 stores ----
        {
            float gv[4];
#pragma unroll
            for (int k = 0; k < 4; ++k) {
                float sacc = bias4[k];
#pragma unroll
                for (int p = 0; p < 4; ++p)
                    sacc += gp[GPIDX(rl, p, (k << 4) + mj)];
                gv[k] = my_sig(sacc);
            }
            float sacc2 = bias2v;
#pragma unroll
            for (int p = 0; p < 8; ++p)
                sacc2 += gp2[rl * 132 + (p << 4) + mj];
            const float cs1v = my_tanh(sacc2);
            const float tv = tsT[s * BB + r0 + rl];
            const float cadj = creg + cs1v * (tv - 1.0f);
            const float cnew = gv[0] * cadj + gv[1] * gv[3];
            const float hnew = gv[2] * my_tanh(cnew);
            creg = cnew; hsreg += hnew;
            const int gidx = (r0 + rl) * HH + m0 + mj;
            st_devu(&c2n[gidx], packsplit(cnew));
            st_devu(&h2n[gidx], packsplit(hnew));
        }

        // ---- G: drain + hierarchical arrival ----
        asm volatile("s_waitcnt vmcnt(0)" ::: "memory");
        __syncthreads();
        if (tid == 0) {
            unsigned old = __hip_atomic_fetch_add(&arr[grp * 32], 1u,
                                                  __ATOMIC_RELAXED, __HIP_MEMORY_SCOPE_AGENT);
            if (old == 32u * (unsigned)(s + 1) - 1u) {
                unsigned go = __hip_atomic_fetch_add(gar, 1u,
                                                     __ATOMIC_RELAXED, __HIP_MEMORY_SCOPE_AGENT);
                if (go == 8u * (unsigned)(s + 1) - 1u) {
#pragma unroll
                    for (int g = 0; g < 8; ++g)
                        st_devu(&rel[g * 32], (unsigned)(s + 1));
                }
            }
        }
    }

    hsum[(r0 + rl) * HH + m0 + mj] = hsreg;
}

// Tail: sub = relu(tfidf@fcw+b); x = [sub | hsum/512]; 3-layer MLP (fp32).
__global__ void __launch_bounds__(256)
tail_kernel(const float* __restrict__ tfidf, const float* __restrict__ hsum,
            const float* __restrict__ fcw, const float* __restrict__ fcb,
            const float* __restrict__ l1w, const float* __restrict__ l1b,
            const float* __restrict__ l2w, const float* __restrict__ l2b,
            const float* __restrict__ low, const float* __restrict__ lob,
            float* __restrict__ out)
{
    const int row = blockIdx.x;
    const int t = threadIdx.x;
    __shared__ float tf[800];
    __shared__ float xrow[1024];
    __shared__ float y1[256];
    __shared__ float y2[128];

    for (int k = t; k < NTF; k += 256) tf[k] = tfidf[row * NTF + k];
    __syncthreads();

    for (int n = t; n < 512; n += 256) {
        float acc = fcb[n];
        for (int k = 0; k < NTF; ++k) acc += tf[k] * fcw[k * 512 + n];
        xrow[n] = fmaxf(acc, 0.f);
    }
    for (int n = t; n < 512; n += 256)
        xrow[512 + n] = hsum[row * HH + n] * (1.0f / 512.0f);
    __syncthreads();

    {
        float acc = l1b[t];
        for (int k = 0; k < 1024; ++k) acc += xrow[k] * l1w[k * 256 + t];
        y1[t] = fmaxf(acc, 0.f);
    }
    __syncthreads();
    if (t < 128) {
        float acc = l2b[t];
        for (int k = 0; k < 256; ++k) acc += y1[k] * l2w[k * 128 + t];
        y2[t] = fmaxf(acc, 0.f);
    }
    __syncthreads();
    if (t < 2) {
        float acc = lob[t];
        for (int k = 0; k < 128; ++k) acc += y2[k] * low[k * 2 + t];
        out[row * 2 + t] = acc;
    }
}

extern "C" void kernel_launch(void* const* d_in, const int* in_sizes, int n_in,
                              void* d_out, int out_size, void* d_ws, size_t ws_size,
                              hipStream_t stream)
{
    const float* x     = (const float*)d_in[0];
    const float* ts    = (const float*)d_in[1];
    const float* tfidf = (const float*)d_in[2];
    const float* Wall  = (const float*)d_in[3];
    const float* ball  = (const float*)d_in[4];
    const float* Uall  = (const float*)d_in[5];
    const float* bu    = (const float*)d_in[6];
    const float* Wd    = (const float*)d_in[7];
    const float* bd    = (const float*)d_in[8];
    const float* fcw   = (const float*)d_in[9];
    const float* fcb   = (const float*)d_in[10];
    const float* l1w   = (const float*)d_in[11];
    const float* l1b   = (const float*)d_in[12];
    const float* l2w   = (const float*)d_in[13];
    const float* l2b   = (const float*)d_in[14];
    const float* low   = (const float*)d_in[15];
    const float* lob   = (const float*)d_in[16];
    float* out = (float*)d_out;

    unsigned* wsu = (unsigned*)d_ws;
    unsigned* h2a = wsu;
    unsigned* h2b = h2a + BB * HH;
    unsigned* c2a = h2b + BB * HH;
    unsigned* c2b = c2a + BB * HH;
    float* hs  = (float*)(c2b + BB * HH);
    float* tsT = hs + BB * HH;
    unsigned* barv = (unsigned*)(tsT + BB * SS);               // 1024 u32
    unsigned short* B1 = (unsigned short*)(barv + 1024);
    unsigned short* B2 = B1 + (size_t)32 * 32 * 4 * 2 * 64 * 8;  // B1 = 16.8MB

    prep_split<<<1152, 256, 0, stream>>>(Wall, Uall, Wd, B1, B2);

    void* args[] = { (void*)&x, (void*)&ts, (void*)&ball, (void*)&bu, (void*)&bd,
                     (void*)&B1, (void*)&B2,
                     (void*)&h2a, (void*)&h2b, (void*)&c2a, (void*)&c2b,
                     (void*)&hs, (void*)&tsT, (void*)&barv };
    hipLaunchCooperativeKernel((void*)lstm_persistent, dim3(256), dim3(512), args, 0, stream);

    tail_kernel<<<256, 256, 0, stream>>>(tfidf, hs, fcw, fcb, l1w, l1b, l2w, l2b,
                                         low, lob, out);
}

// Round 12
// 4939.699 us; speedup vs baseline: 2.8447x; 1.3033x over previous
//
#include <hip/hip_runtime.h>
#include <hip/hip_cooperative_groups.h>

namespace cg = cooperative_groups;

#define BB 256
#define SS 512
#define EE 512
#define HH 512
#define G4 2048
#define NTF 799

typedef __attribute__((ext_vector_type(8))) short bf16x8;
typedef __attribute__((ext_vector_type(4))) float f32x4;

__device__ __forceinline__ float my_sig(float v) { return 1.0f / (1.0f + __expf(-v)); }
__device__ __forceinline__ float my_tanh(float v) { float e = __expf(2.0f * v); return 1.0f - 2.0f / (e + 1.0f); }

__device__ __forceinline__ unsigned short f2bf(float f) {   // RNE fp32->bf16
    unsigned u = __builtin_bit_cast(unsigned, f);
    u = (u + 0x7FFFu + ((u >> 16) & 1u)) >> 16;
    return (unsigned short)u;
}
__device__ __forceinline__ float bf2f(unsigned short h) {
    unsigned u = ((unsigned)h) << 16;
    return __builtin_bit_cast(float, u);
}
__device__ __forceinline__ unsigned packsplit(float f) {
    unsigned short hi = f2bf(f);
    unsigned short lo = f2bf(f - bf2f(hi));
    return ((unsigned)hi << 16) | (unsigned)lo;
}
__device__ __forceinline__ bf16x8 unhi(uint4 a, uint4 b) {
    union { unsigned u[4]; bf16x8 v; } r;
    r.u[0] = __builtin_amdgcn_perm(a.y, a.x, 0x07060302u);
    r.u[1] = __builtin_amdgcn_perm(a.w, a.z, 0x07060302u);
    r.u[2] = __builtin_amdgcn_perm(b.y, b.x, 0x07060302u);
    r.u[3] = __builtin_amdgcn_perm(b.w, b.z, 0x07060302u);
    return r.v;
}
__device__ __forceinline__ bf16x8 unlo(uint4 a, uint4 b) {
    union { unsigned u[4]; bf16x8 v; } r;
    r.u[0] = __builtin_amdgcn_perm(a.y, a.x, 0x05040100u);
    r.u[1] = __builtin_amdgcn_perm(a.w, a.z, 0x05040100u);
    r.u[2] = __builtin_amdgcn_perm(b.y, b.x, 0x05040100u);
    r.u[3] = __builtin_amdgcn_perm(b.w, b.z, 0x05040100u);
    return r.v;
}

// sc1 coherent accesses (verified r4-r11); nt = non-temporal (skip L3 churn)
__device__ __forceinline__ void ld4_sc1(uint4& d, const unsigned* p) {
    asm volatile("global_load_dwordx4 %0, %1, off sc0 sc1" : "=v"(d) : "v"(p));
}
__device__ __forceinline__ void ld4_nt(uint4& d, const uint4* p) {
    asm volatile("global_load_dwordx4 %0, %1, off nt" : "=v"(d) : "v"(p));
}
__device__ __forceinline__ void st_devu(unsigned* p, unsigned v) {
    __hip_atomic_store(p, v, __ATOMIC_RELAXED, __HIP_MEMORY_SCOPE_AGENT);
}
__device__ __forceinline__ unsigned ld_devu(const unsigned* p) {
    return __hip_atomic_load(p, __ATOMIC_RELAXED, __HIP_MEMORY_SCOPE_AGENT);
}

// ---------------------------------------------------------------------------
// Prep: split weights into bf16 hi/lo MFMA B-fragments (verbatim r8-r11).
// ---------------------------------------------------------------------------
__global__ void __launch_bounds__(256)
prep_split(const float* __restrict__ Wall, const float* __restrict__ Uall,
           const float* __restrict__ Wd,
           unsigned short* __restrict__ B1, unsigned short* __restrict__ B2)
{
    const int t = blockIdx.x * 256 + threadIdx.x;
    if (t < 262144) {
        const int lane = t & 63, wc = (t >> 6) & 3, kc = (t >> 8) & 31, cgi = t >> 13;
        const int kb = ((kc & 15) << 5) + ((lane >> 4) << 3);
        const int col = (wc << 9) + (cgi << 4) + (lane & 15);
        const float* src = (kc < 16) ? Wall : Uall;
        bf16x8 vh, vl;
#pragma unroll
        for (int j = 0; j < 8; ++j) {
            float f = src[(size_t)(kb + j) * G4 + col];
            unsigned short h16 = f2bf(f);
            vh[j] = (short)h16;
            vl[j] = (short)f2bf(f - bf2f(h16));
        }
        const int g = t >> 6;
        *(bf16x8*)(B1 + ((size_t)(g * 2 + 0) * 64 + lane) * 8) = vh;
        *(bf16x8*)(B1 + ((size_t)(g * 2 + 1) * 64 + lane) * 8) = vl;
    } else if (t < 262144 + 32768) {
        const int u = t - 262144;
        const int lane = u & 63, kch = (u >> 6) & 15, cgi = u >> 10;
        const int kb = (kch << 5) + ((lane >> 4) << 3);
        const int col = (cgi << 4) + (lane & 15);
        bf16x8 vh, vl;
#pragma unroll
        for (int j = 0; j < 8; ++j) {
            float f = Wd[(size_t)(kb + j) * HH + col];
            unsigned short h16 = f2bf(f);
            vh[j] = (short)h16;
            vl[j] = (short)f2bf(f - bf2f(h16));
        }
        const int g = u >> 6;
        *(bf16x8*)(B2 + ((size_t)(g * 2 + 0) * 64 + lane) * 8) = vh;
        *(bf16x8*)(B2 + ((size_t)(g * 2 + 1) * 64 + lane) * 8) = vl;
    }
}

// Prep: pack x -> hi|lo u32 (same layout), so step staging is a pure copy.
__global__ void __launch_bounds__(256)
prep_pack(const float* __restrict__ x, unsigned* __restrict__ xp)
{
    const size_t i = (size_t)blockIdx.x * 256 + threadIdx.x;   // over 16.7M float4s
    float4 v = ((const float4*)x)[i];
    uint4 p;
    p.x = packsplit(v.x); p.y = packsplit(v.y);
    p.z = packsplit(v.z); p.w = packsplit(v.w);
    ((uint4*)xp)[i] = p;
}

#define B1FRAG(kcv, wcv, term) (*(const bf16x8*)(B1 +                          \
    ((size_t)(((cgi * 32 + (kcv)) * 4 + (wcv)) * 2 + (term)) * 64 + lane) * 8))
#define B2FRAG(kchv, term) (*(const bf16x8*)(B2 +                              \
    ((size_t)((cgi * 16 + (kchv)) * 2 + (term)) * 64 + lane) * 8))

// gate-partial LDS index, bank-hashed (2-way max = free)
#define GPIDX(row, slot, col)                                                  \
    ((row) * 256 + (slot) * 64 + ((col) ^ (((((row) & 3) ^ (((row) >> 2) & 3))) << 4)))

// ---------------------------------------------------------------------------
// Persistent time-LSTM. 256 blocks x 512 threads. Wave (kq, ch) owns K-window
// kq*128 and gate-col half ch*32. W/Wd frags register-resident; U streamed
// from XCD-local L2 (double-buffered under phase-A MFMAs). Sync scope is the
// 32 blocks sharing a row-group (rg): ONE relaxed counter per rg, arrival
// after store-drain, poll >= 32*s. No data crosses rg groups.
// ---------------------------------------------------------------------------
__global__ void __launch_bounds__(512) __attribute__((amdgpu_waves_per_eu(2)))
lstm_persistent(const float* __restrict__ x, const unsigned* __restrict__ xp,
                const int use_xp, const float* __restrict__ ts,
                const float* __restrict__ ball, const float* __restrict__ bu,
                const float* __restrict__ bd,
                const unsigned short* __restrict__ B1,
                const unsigned short* __restrict__ B2,
                unsigned* __restrict__ h2a, unsigned* __restrict__ h2b,
                unsigned* __restrict__ c2a, unsigned* __restrict__ c2b,
                float* __restrict__ hsum, float* __restrict__ tsT,
                unsigned* __restrict__ barv)
{
    cg::grid_group grid = cg::this_grid();
    const int tid = threadIdx.x;
    const int bid = blockIdx.x;
    const int gtid = (bid << 9) + tid;

    for (int i = gtid; i < BB * HH; i += 131072) { h2a[i] = 0u; c2a[i] = 0u; }
    for (int i = gtid; i < BB * SS; i += 131072) {
        int b = i >> 9, s = i & 511;
        tsT[s * BB + b] = ts[i];
    }
    if (gtid < 1024) barv[gtid] = 0u;
    grid.sync();

    // XCD-aware bijective relabeling (L2 affinity for the 4 cgi slices/XCD)
    const int xcd = bid & 7, tt = bid >> 3;
    const int cgi = (xcd << 2) | (tt & 3);   // 0..31 -> m0
    const int rg  = tt >> 2;                 // 0..7  -> r0 (sync group!)
    const int r0  = rg << 5;
    const int m0  = cgi << 4;

    const int wid = tid >> 6, lane = tid & 63;
    const int lrow = lane & 15, lk8 = lane >> 4;
    const int kq = wid & 3, ch = wid >> 2;
    const int srow = tid >> 4, scb = tid & 15;
    const int rl = srow, mj = scb;

    __shared__ __align__(16) unsigned R1[32 * 512];  // AX -> AC
    __shared__ __align__(16) unsigned R2[32 * 512];  // AH -> partials
    uint4* R1v = (uint4*)R1;
    uint4* R2v = (uint4*)R2;
    float* gp  = (float*)R2;              // [32][4][64] hashed, 32KB
    float* gp2 = (float*)(R2 + 8192);     // [32][132], 17KB

    unsigned* arr = barv;                 // per-rg counter at barv[rg*64]
    const int myline = rg << 6;

    // register-resident: W frags + Wd frags
    bf16x8 wfh[4][2], wfl[4][2], d2h[2], d2l[2];
#pragma unroll
    for (int q = 0; q < 4; ++q)
#pragma unroll
        for (int wcl = 0; wcl < 2; ++wcl) {
            wfh[q][wcl] = B1FRAG((kq << 2) + q, (ch << 1) + wcl, 0);
            wfl[q][wcl] = B1FRAG((kq << 2) + q, (ch << 1) + wcl, 1);
        }
#pragma unroll
    for (int e = 0; e < 2; ++e) {
        d2h[e] = B2FRAG((wid << 1) + e, 0);
        d2l[e] = B2FRAG((wid << 1) + e, 1);
    }

    float bias4[4];
#pragma unroll
    for (int k = 0; k < 4; ++k)
        bias4[k] = ball[(k << 9) + m0 + mj] + bu[(k << 9) + m0 + mj];
    const float bias2v = bd[m0 + mj];

    float creg = 0.f, hsreg = 0.f;

#pragma unroll 1
    for (int s = 0; s < SS; ++s) {
        const unsigned* h2p = (s & 1) ? h2b : h2a;
        const unsigned* c2p = (s & 1) ? c2b : c2a;
        unsigned* h2n = (s & 1) ? h2a : h2b;
        unsigned* c2n = (s & 1) ? c2a : c2b;

        // ---- A: stage AX <- x(s) ----
        __syncthreads();                      // prev-step partial reads done
        if (use_xp) {
            const uint4* xpp = (const uint4*)(xp + (size_t)(r0 + srow) * (SS * EE)
                                              + (size_t)s * EE);
            uint4 xv[8];
#pragma unroll
            for (int j = 0; j < 8; ++j) ld4_nt(xv[j], xpp + (scb + (j << 4)));
            asm volatile("s_waitcnt vmcnt(0)" ::: "memory");
            __builtin_amdgcn_sched_barrier(0);
#pragma unroll
            for (int j = 0; j < 8; ++j) {
                const int ci = scb + (j << 4);
                R1v[srow * 128 + (ci ^ (srow & 7))] = xv[j];
            }
        } else {
            const float* xfp = x + (size_t)(r0 + srow) * (SS * EE) + (size_t)s * EE;
#pragma unroll
            for (int j = 0; j < 8; ++j) {
                const int ci = scb + (j << 4);
                float4 v = *(const float4*)(xfp + (ci << 2));
                uint4 pk;
                pk.x = packsplit(v.x); pk.y = packsplit(v.y);
                pk.z = packsplit(v.z); pk.w = packsplit(v.w);
                R1v[srow * 128 + (ci ^ (srow & 7))] = pk;
            }
        }
        __syncthreads();

        // ---- phase A: x.U MFMAs, U frags streamed (double-buffered) ----
        f32x4 acc[2][2];
        acc[0][0] = acc[0][1] = acc[1][0] = acc[1][1] = (f32x4){0.f, 0.f, 0.f, 0.f};
        {
            bf16x8 ufh[2][2], ufl[2][2];
#pragma unroll
            for (int wcl = 0; wcl < 2; ++wcl) {
                ufh[0][wcl] = B1FRAG(16 + (kq << 2), (ch << 1) + wcl, 0);
                ufl[0][wcl] = B1FRAG(16 + (kq << 2), (ch << 1) + wcl, 1);
            }
#pragma unroll
            for (int q = 0; q < 4; ++q) {
                const int cur = q & 1, nxt = cur ^ 1;
                if (q < 3) {
#pragma unroll
                    for (int wcl = 0; wcl < 2; ++wcl) {
                        ufh[nxt][wcl] = B1FRAG(16 + (kq << 2) + q + 1, (ch << 1) + wcl, 0);
                        ufl[nxt][wcl] = B1FRAG(16 + (kq << 2) + q + 1, (ch << 1) + wcl, 1);
                    }
                }
                const int kcp = (kq << 2) + q;
#pragma unroll
                for (int wr = 0; wr < 2; ++wr) {
                    const int row_ = (wr << 4) | lrow;
                    const int cb_  = (kcp << 3) + (lk8 << 1);
                    uint4 qa = R1v[row_ * 128 + (cb_ ^ (row_ & 7))];
                    uint4 qb = R1v[row_ * 128 + ((cb_ + 1) ^ (row_ & 7))];
                    bf16x8 ah = unhi(qa, qb), al = unlo(qa, qb);
#pragma unroll
                    for (int wcl = 0; wcl < 2; ++wcl) {
                        acc[wr][wcl] = __builtin_amdgcn_mfma_f32_16x16x32_bf16(ah, ufh[cur][wcl], acc[wr][wcl], 0, 0, 0);
                        acc[wr][wcl] = __builtin_amdgcn_mfma_f32_16x16x32_bf16(ah, ufl[cur][wcl], acc[wr][wcl], 0, 0, 0);
                        acc[wr][wcl] = __builtin_amdgcn_mfma_f32_16x16x32_bf16(al, ufh[cur][wcl], acc[wr][wcl], 0, 0, 0);
                    }
                }
            }
        }

        // ---- B: per-rg wait: all 32 same-rg blocks arrived for step s-1 ----
        if (tid == 0) {
            const unsigned tgt = 32u * (unsigned)s;
            while (ld_devu(&arr[myline]) < tgt)
                __builtin_amdgcn_s_sleep(4);
        }
        __syncthreads();
        asm volatile("" ::: "memory");

        // ---- C: fused h+c load (16 dwordx4, vmcnt(8)/vmcnt(0) split) ----
        {
            const unsigned* hp = h2p + (r0 + srow) * HH;
            const unsigned* cp = c2p + (r0 + srow) * HH;
            uint4 hv[8], cv[8];
#pragma unroll
            for (int j = 0; j < 8; ++j) ld4_sc1(hv[j], hp + ((scb + (j << 4)) << 2));
#pragma unroll
            for (int j = 0; j < 8; ++j) ld4_sc1(cv[j], cp + ((scb + (j << 4)) << 2));
            asm volatile("s_waitcnt vmcnt(8)" ::: "memory");
            __builtin_amdgcn_sched_barrier(0);
#pragma unroll
            for (int j = 0; j < 8; ++j) {
                const int ci = scb + (j << 4);
                R2v[srow * 128 + (ci ^ (srow & 7))] = hv[j];
            }
            asm volatile("s_waitcnt vmcnt(0)" ::: "memory");
            __builtin_amdgcn_sched_barrier(0);
#pragma unroll
            for (int j = 0; j < 8; ++j) {
                const int ci = scb + (j << 4);
                R1v[srow * 128 + (ci ^ (srow & 7))] = cv[j];
            }
        }
        __syncthreads();

        // ---- phase B: h.W MFMAs (resident frags) into same acc; then G2 ----
#pragma unroll
        for (int q = 0; q < 4; ++q) {
            const int kcp = (kq << 2) + q;
#pragma unroll
            for (int wr = 0; wr < 2; ++wr) {
                const int row_ = (wr << 4) | lrow;
                const int cb_  = (kcp << 3) + (lk8 << 1);
                uint4 qa = R2v[row_ * 128 + (cb_ ^ (row_ & 7))];
                uint4 qb = R2v[row_ * 128 + ((cb_ + 1) ^ (row_ & 7))];
                bf16x8 ah = unhi(qa, qb), al = unlo(qa, qb);
#pragma unroll
                for (int wcl = 0; wcl < 2; ++wcl) {
                    acc[wr][wcl] = __builtin_amdgcn_mfma_f32_16x16x32_bf16(ah, wfh[q][wcl], acc[wr][wcl], 0, 0, 0);
                    acc[wr][wcl] = __builtin_amdgcn_mfma_f32_16x16x32_bf16(ah, wfl[q][wcl], acc[wr][wcl], 0, 0, 0);
                    acc[wr][wcl] = __builtin_amdgcn_mfma_f32_16x16x32_bf16(al, wfh[q][wcl], acc[wr][wcl], 0, 0, 0);
                }
            }
        }
        f32x4 acc2[2];
        acc2[0] = (f32x4){0.f, 0.f, 0.f, 0.f};
        acc2[1] = (f32x4){0.f, 0.f, 0.f, 0.f};
#pragma unroll
        for (int e = 0; e < 2; ++e) {
            const int kch = (wid << 1) + e;
#pragma unroll
            for (int wr = 0; wr < 2; ++wr) {
                const int row_ = (wr << 4) | lrow;
                const int cb_  = (kch << 3) + (lk8 << 1);
                uint4 qa = R1v[row_ * 128 + (cb_ ^ (row_ & 7))];
                uint4 qb = R1v[row_ * 128 + ((cb_ + 1) ^ (row_ & 7))];
                bf16x8 ah = unhi(qa, qb), al = unlo(qa, qb);
                acc2[wr] = __builtin_amdgcn_mfma_f32_16x16x32_bf16(ah, d2h[e], acc2[wr], 0, 0, 0);
                acc2[wr] = __builtin_amdgcn_mfma_f32_16x16x32_bf16(ah, d2l[e], acc2[wr], 0, 0, 0);
                acc2[wr] = __builtin_amdgcn_mfma_f32_16x16x32_bf16(al, d2h[e], acc2[wr], 0, 0, 0);
            }
        }
        __syncthreads();   // AH/AC reads done before partials overwrite R2

        // ---- E: partial writes ----
#pragma unroll
        for (int wr = 0; wr < 2; ++wr)
#pragma unroll
            for (int wcl = 0; wcl < 2; ++wcl)
#pragma unroll
                for (int i = 0; i < 4; ++i)
                    gp[GPIDX((wr << 4) + (lk8 << 2) + i, kq, ((ch << 1) + wcl) * 16 + lrow)] = acc[wr][wcl][i];
#pragma unroll
        for (int wr = 0; wr < 2; ++wr)
#pragma unroll
            for (int i = 0; i < 4; ++i)
                gp2[((wr << 4) + (lk8 << 2) + i) * 132 + (wid << 4) + lrow] = acc2[wr][i];
        __syncthreads();

        // ---- F: reduce + update + sc1 stores ----
        {
            float gv[4];
#pragma unroll
            for (int k = 0; k < 4; ++k) {
                float sacc = bias4[k];
#pragma unroll
                for (int p = 0; p < 4; ++p)
                    sacc += gp[GPIDX(rl, p, (k << 4) + mj)];
                gv[k] = my_sig(sacc);
            }
            float sacc2 = bias2v;
#pragma unroll
            for (int p = 0; p < 8; ++p)
                sacc2 += gp2[rl * 132 + (p << 4) + mj];
            const float cs1v = my_tanh(sacc2);
            const float tv = tsT[s * BB + r0 + rl];
            const float cadj = creg + cs1v * (tv - 1.0f);
            const float cnew = gv[0] * cadj + gv[1] * gv[3];
            const float hnew = gv[2] * my_tanh(cnew);
            creg = cnew; hsreg += hnew;
            const int gidx = (r0 + rl) * HH + m0 + mj;
            st_devu(&c2n[gidx], packsplit(cnew));
            st_devu(&h2n[gidx], packsplit(hnew));
        }

        // ---- G: drain + per-rg arrival (1 add, no aggregation tree) ----
        asm volatile("s_waitcnt vmcnt(0)" ::: "memory");
        __syncthreads();
        if (tid == 0)
            __hip_atomic_fetch_add(&arr[myline], 1u, __ATOMIC_RELAXED,
                                   __HIP_MEMORY_SCOPE_AGENT);
    }

    hsum[(r0 + rl) * HH + m0 + mj] = hsreg;
}

// Tail: sub = relu(tfidf@fcw+b); x = [sub | hsum/512]; 3-layer MLP (fp32).
__global__ void __launch_bounds__(256)
tail_kernel(const float* __restrict__ tfidf, const float* __restrict__ hsum,
            const float* __restrict__ fcw, const float* __restrict__ fcb,
            const float* __restrict__ l1w, const float* __restrict__ l1b,
            const float* __restrict__ l2w, const float* __restrict__ l2b,
            const float* __restrict__ low, const float* __restrict__ lob,
            float* __restrict__ out)
{
    const int row = blockIdx.x;
    const int t = threadIdx.x;
    __shared__ float tf[800];
    __shared__ float xrow[1024];
    __shared__ float y1[256];
    __shared__ float y2[128];

    for (int k = t; k < NTF; k += 256) tf[k] = tfidf[row * NTF + k];
    __syncthreads();

    for (int n = t; n < 512; n += 256) {
        float acc = fcb[n];
        for (int k = 0; k < NTF; ++k) acc += tf[k] * fcw[k * 512 + n];
        xrow[n] = fmaxf(acc, 0.f);
    }
    for (int n = t; n < 512; n += 256)
        xrow[512 + n] = hsum[row * HH + n] * (1.0f / 512.0f);
    __syncthreads();

    {
        float acc = l1b[t];
        for (int k = 0; k < 1024; ++k) acc += xrow[k] * l1w[k * 256 + t];
        y1[t] = fmaxf(acc, 0.f);
    }
    __syncthreads();
    if (t < 128) {
        float acc = l2b[t];
        for (int k = 0; k < 256; ++k) acc += y1[k] * l2w[k * 128 + t];
        y2[t] = fmaxf(acc, 0.f);
    }
    __syncthreads();
    if (t < 2) {
        float acc = lob[t];
        for (int k = 0; k < 128; ++k) acc += y2[k] * low[k * 2 + t];
        out[row * 2 + t] = acc;
    }
}

extern "C" void kernel_launch(void* const* d_in, const int* in_sizes, int n_in,
                              void* d_out, int out_size, void* d_ws, size_t ws_size,
                              hipStream_t stream)
{
    const float* x     = (const float*)d_in[0];
    const float* ts    = (const float*)d_in[1];
    const float* tfidf = (const float*)d_in[2];
    const float* Wall  = (const float*)d_in[3];
    const float* ball  = (const float*)d_in[4];
    const float* Uall  = (const float*)d_in[5];
    const float* bu    = (const float*)d_in[6];
    const float* Wd    = (const float*)d_in[7];
    const float* bd    = (const float*)d_in[8];
    const float* fcw   = (const float*)d_in[9];
    const float* fcb   = (const float*)d_in[10];
    const float* l1w   = (const float*)d_in[11];
    const float* l1b   = (const float*)d_in[12];
    const float* l2w   = (const float*)d_in[13];
    const float* l2b   = (const float*)d_in[14];
    const float* low   = (const float*)d_in[15];
    const float* lob   = (const float*)d_in[16];
    float* out = (float*)d_out;

    unsigned* wsu = (unsigned*)d_ws;
    unsigned* h2a = wsu;
    unsigned* h2b = h2a + BB * HH;
    unsigned* c2a = h2b + BB * HH;
    unsigned* c2b = c2a + BB * HH;
    float* hs  = (float*)(c2b + BB * HH);
    float* tsT = hs + BB * HH;
    unsigned* barv = (unsigned*)(tsT + BB * SS);               // 1024 u32
    unsigned short* B1 = (unsigned short*)(barv + 1024);
    unsigned short* B2 = B1 + (size_t)32 * 32 * 4 * 2 * 64 * 8;   // B1 = 16.8MB
    unsigned* xpk = (unsigned*)(B2 + (size_t)32 * 16 * 2 * 64 * 8); // after 2.1MB B2
    const size_t need = ((char*)(xpk + (size_t)BB * SS * EE)) - (char*)d_ws;
    const int use_xp = (ws_size >= need) ? 1 : 0;

    prep_split<<<1152, 256, 0, stream>>>(Wall, Uall, Wd, B1, B2);
    if (use_xp)
        prep_pack<<<65536, 256, 0, stream>>>(x, xpk);

    void* args[] = { (void*)&x, (void*)&xpk, (void*)&use_xp, (void*)&ts,
                     (void*)&ball, (void*)&bu, (void*)&bd,
                     (void*)&B1, (void*)&B2,
                     (void*)&h2a, (void*)&h2b, (void*)&c2a, (void*)&c2b,
                     (void*)&hs, (void*)&tsT, (void*)&barv };
    hipLaunchCooperativeKernel((void*)lstm_persistent, dim3(256), dim3(512), args, 0, stream);

    tail_kernel<<<256, 256, 0, stream>>>(tfidf, hs, fcw, fcb, l1w, l1b, l2w, l2b,
                                         low, lob, out);
}